// Round 2
// baseline (426.395 us; speedup 1.0000x reference)
//
#include <hip/hip_runtime.h>

#define NE 500000      // edges
#define DIMK 256       // embedding dim
#define H1 128
#define H2 64
#define EPSBN 1e-5f
#define TILE1 128
#define GRID1 512
#define NT1 3907                 // tiles of 128 edges
#define GRID2 512
#define NJ2 1954                 // jobs of 256 edges

typedef _Float16 half8 __attribute__((ext_vector_type(8)));
typedef float f32x4 __attribute__((ext_vector_type(4)));
typedef unsigned short ushort8 __attribute__((ext_vector_type(8)));

typedef const __attribute__((address_space(1))) void* gas1_t;
typedef __attribute__((address_space(3))) void* las3_t;

static __device__ __forceinline__ half8 habs8(half8 x) {
  ushort8 u = __builtin_bit_cast(ushort8, x);
  u &= (unsigned short)0x7FFF;
  return __builtin_bit_cast(half8, u);
}
static __device__ __forceinline__ float h2f(unsigned int u) {
  return (float)__builtin_bit_cast(_Float16, (unsigned short)(u & 0xffff));
}
static __device__ __forceinline__ unsigned packf16(float a, float b) {
  unsigned lo = (unsigned)__builtin_bit_cast(unsigned short, (_Float16)a);
  unsigned hi = (unsigned)__builtin_bit_cast(unsigned short, (_Float16)b);
  return lo | (hi << 16);
}
// async global->LDS, 16B per lane; LDS dest wave-uniform base + lane*16
static __device__ __forceinline__ void gload_lds16(const _Float16* src, _Float16* dst) {
  __builtin_amdgcn_global_load_lds((gas1_t)src, (las3_t)dst, 16, 0, 0);
}

#define WAITV(N) asm volatile("s_waitcnt vmcnt(" #N ")" ::: "memory")
#define SB0 __builtin_amdgcn_sched_barrier(0)

// c0[j] = b1[j] + step @ W1[768:800, j]
__global__ void k_prep(const float* __restrict__ W1, const float* __restrict__ b1,
                       const float* __restrict__ step, float* __restrict__ c0) {
  const int j = threadIdx.x;
  if (j < H1) {
    float a = b1[j];
#pragma unroll
    for (int tt = 0; tt < 32; ++tt) a += step[tt] * W1[(768 + tt) * H1 + j];
    c0[j] = a;
  }
}

// fp32 emb -> fp16 copy (12.8M elems, 8/thread, exact grid)
__global__ void k_prep16(const float* __restrict__ emb, _Float16* __restrict__ embh) {
  const int i = (blockIdx.x * 256 + threadIdx.x) * 8;
  const float4 a = *(const float4*)(emb + i);
  const float4 b = *(const float4*)(emb + i + 4);
  half8 h;
  h[0] = (_Float16)a.x; h[1] = (_Float16)a.y; h[2] = (_Float16)a.z; h[3] = (_Float16)a.w;
  h[4] = (_Float16)b.x; h[5] = (_Float16)b.y; h[6] = (_Float16)b.z; h[7] = (_Float16)b.w;
  *(half8*)(embh + i) = h;
}

// Build fragment-ordered B for layer1: bfrag[(s*64+kc*8+c)*64*8 + lane*8 + j]
//   = W1[s*256 + kc*32 + (lane>>4)*8 + j][c*16 + (lane&15)]   (fp16)
__global__ void k_prepB(const float* __restrict__ W1, _Float16* __restrict__ bfrag) {
  const int g = blockIdx.x * 256 + threadIdx.x;
  const int lane = g & 63, f = g >> 6;
  const int c = f & 7, kc = (f >> 3) & 7, s = f >> 6;
  const int row0 = s * 256 + kc * 32 + (lane >> 4) * 8;
  const int col = c * 16 + (lane & 15);
  half8 h;
#pragma unroll
  for (int j = 0; j < 8; ++j) h[j] = (_Float16)W1[(row0 + j) * H1 + col];
  *(half8*)(bfrag + (size_t)g * 8) = h;
}

// Stage one kc-slice of B (24KB = 1536 half8) into LDS buffer q. 6 issues/thread.
#define STAGE1(q, kcv) do {                                                   \
    _Pragma("unroll")                                                         \
    for (int jj = 0; jj < 6; ++jj) {                                          \
      const int sc = jj * 4 + w;                                              \
      const int ff = (sc >> 3) * 64 + (kcv) * 8 + (sc & 7);                   \
      gload_lds16(bfrag + ((size_t)ff * 64 + lane) * 8,                       \
                  s_B + (size_t)(q) * 12288 + sc * 512);                      \
    }                                                                         \
  } while (0)

// prefetch A-gathers for kc slice (4 loads/thread) into reg buffer pb
#define PREFA(pb, kcv) do {                                                   \
    u[pb][0] = *(const half8*)(pu[0] + (kcv) * 32);                           \
    u[pb][1] = *(const half8*)(pu[1] + (kcv) * 32);                           \
    v[pb][0] = *(const half8*)(pv[0] + (kcv) * 32);                           \
    v[pb][1] = *(const half8*)(pv[1] + (kcv) * 32);                           \
  } while (0)

#define MFMA_KC(pb) do {                                                      \
    half8 d0 = habs8(u[pb][0] - v[pb][0]);                                    \
    half8 d1 = habs8(u[pb][1] - v[pb][1]);                                    \
    const half8* bq = (const half8*)s_B + (size_t)(pb) * 1536 + lane;         \
    _Pragma("unroll")                                                         \
    for (int c = 0; c < 8; ++c) {                                             \
      half8 bu = bq[c * 64], bv = bq[512 + c * 64], bd = bq[1024 + c * 64];   \
      acc[0][c] = __builtin_amdgcn_mfma_f32_16x16x32_f16(u[pb][0], bu, acc[0][c], 0, 0, 0); \
      acc[1][c] = __builtin_amdgcn_mfma_f32_16x16x32_f16(u[pb][1], bu, acc[1][c], 0, 0, 0); \
      acc[0][c] = __builtin_amdgcn_mfma_f32_16x16x32_f16(v[pb][0], bv, acc[0][c], 0, 0, 0); \
      acc[1][c] = __builtin_amdgcn_mfma_f32_16x16x32_f16(v[pb][1], bv, acc[1][c], 0, 0, 0); \
      acc[0][c] = __builtin_amdgcn_mfma_f32_16x16x32_f16(d0, bd, acc[0][c], 0, 0, 0); \
      acc[1][c] = __builtin_amdgcn_mfma_f32_16x16x32_f16(d1, bd, acc[1][c], 0, 0, 0); \
    }                                                                         \
  } while (0)

// Layer 1: MFMA fp16, 128-edge x 128-col tiles, single barrier per kc,
// counted vmcnt, A-gathers and B-stage both prefetched one kc ahead.
__global__ __launch_bounds__(256, 2)
void k_layer1(const _Float16* __restrict__ embh, const void* __restrict__ eidx_raw,
              const float* __restrict__ grad, const float* __restrict__ W1,
              const float* __restrict__ c0, const _Float16* __restrict__ bfrag,
              _Float16* __restrict__ x1, float* __restrict__ p1) {
  __shared__ __align__(16) _Float16 s_B[2 * 12288];   // 2 x 24KB B slices
  __shared__ float s_sum[128], s_sq[128];

  const int t = threadIdx.x, bid = blockIdx.x;
  const int w = t >> 6, lane = t & 63, quad = lane >> 4, m15 = lane & 15;

  if (t < 128) { s_sum[t] = 0.f; s_sq[t] = 0.f; }

  const unsigned* ew = (const unsigned*)eidx_raw;
  const bool is64 = ((ew[1] | ew[3] | ew[5] | ew[7]) == 0u);
  const int* e32 = (const int*)eidx_raw;
  const long long* e64 = (const long long*)eidx_raw;

  float st_s[8] = {0, 0, 0, 0, 0, 0, 0, 0}, st_q[8] = {0, 0, 0, 0, 0, 0, 0, 0};

  // per-lane folded weight/bias registers (fixed per lane across tiles)
  float wgr[8], c0r[8];
#pragma unroll
  for (int c = 0; c < 8; ++c) {
    wgr[c] = W1[800 * H1 + c * 16 + m15];
    c0r[c] = c0[c * 16 + m15];
  }

  // ---- prologue: first tile indices, pointers, stage(kc0), prefA(kc0), grad
  int tile = bid;
  int base = tile * TILE1;
  const int r0 = w * 32 + m15;
  int cs0, cs1, cd0, cd1;
  {
    int ea = base + r0;      if (ea >= NE) ea = NE - 1;
    int eb = base + r0 + 16; if (eb >= NE) eb = NE - 1;
    if (is64) { cs0 = (int)e64[ea]; cs1 = (int)e64[eb]; cd0 = (int)e64[NE + ea]; cd1 = (int)e64[NE + eb]; }
    else      { cs0 = e32[ea];      cs1 = e32[eb];      cd0 = e32[NE + ea];      cd1 = e32[NE + eb]; }
  }
  WAITV(0); SB0;
  const _Float16 *pu[2], *pv[2], *pun[2], *pvn[2];
  pu[0] = embh + (size_t)cs0 * DIMK + quad * 8;
  pu[1] = embh + (size_t)cs1 * DIMK + quad * 8;
  pv[0] = embh + (size_t)cd0 * DIMK + quad * 8;
  pv[1] = embh + (size_t)cd1 * DIMK + quad * 8;

  half8 u[2][2], v[2][2];
  f32x4 gr[2], grn[2];

  STAGE1(0, 0);                 // 6 loads
  PREFA(0, 0);                  // 4 loads
  gr[0] = *(const f32x4*)(grad + base + w * 32 + quad * 4);        // 2 loads
  gr[1] = *(const f32x4*)(grad + base + w * 32 + 16 + quad * 4);
  // outstanding entering loop: [stage6][prefA4][grad2]

  int n_s0 = 0, n_s1 = 0, n_d0 = 0, n_d1 = 0;

  for (; tile < NT1; ) {
    base = tile * TILE1;
    const int bn = (tile + GRID1 < NT1) ? (tile + GRID1) * TILE1 : 0;

    f32x4 acc[2][8];
#pragma unroll
    for (int r = 0; r < 2; ++r)
#pragma unroll
      for (int c = 0; c < 8; ++c) acc[r][c] = (f32x4)0.f;

#pragma unroll
    for (int kc = 0; kc < 8; ++kc) {
      // (1) drain this kc's B stage (counted: leave younger prefA/grad/idx/stores)
      if (kc == 0)      WAITV(6);
      else if (kc == 6) WAITV(8);
      else              WAITV(4);
      SB0;
      __builtin_amdgcn_s_barrier();
      SB0;
      // (2) stage next slice (tile-independent; kc7 stages next tile's kc0)
      if (kc < 7) STAGE1((kc + 1) & 1, kc + 1);
      else        STAGE1(0, 0);
      // (3) drain prefA(kc) [+idx at kc6]; younger = just-issued stage (6)
      WAITV(6);
      SB0;
      // (4) issue next prefetches
      if (kc < 6) {
        PREFA((kc + 1) & 1, kc + 1);
        if (kc == 5) {          // next-tile indices (4 loads)
          int ea = bn + r0;      if (ea >= NE) ea = NE - 1;
          int eb = bn + r0 + 16; if (eb >= NE) eb = NE - 1;
          if (is64) { n_s0 = (int)e64[ea]; n_s1 = (int)e64[eb]; n_d0 = (int)e64[NE + ea]; n_d1 = (int)e64[NE + eb]; }
          else      { n_s0 = e32[ea];      n_s1 = e32[eb];      n_d0 = e32[NE + ea];      n_d1 = e32[NE + eb]; }
        }
      } else if (kc == 6) {
        pun[0] = embh + (size_t)n_s0 * DIMK + quad * 8;
        pun[1] = embh + (size_t)n_s1 * DIMK + quad * 8;
        pvn[0] = embh + (size_t)n_d0 * DIMK + quad * 8;
        pvn[1] = embh + (size_t)n_d1 * DIMK + quad * 8;
        PREFA(1, 7);
      } else {                  // kc == 7: next tile's A + grad
        u[0][0] = *(const half8*)pun[0];
        u[0][1] = *(const half8*)pun[1];
        v[0][0] = *(const half8*)pvn[0];
        v[0][1] = *(const half8*)pvn[1];
        grn[0] = *(const f32x4*)(grad + bn + w * 32 + quad * 4);
        grn[1] = *(const f32x4*)(grad + bn + w * 32 + 16 + quad * 4);
      }
      // (5) compute
      MFMA_KC(kc & 1);
    }

    // ---- epilogue: relu + stats + packed dword stores (32/lane/tile)
#pragma unroll
    for (int r = 0; r < 2; ++r) {
      const int e0 = base + w * 32 + r * 16 + quad * 4;
#pragma unroll
      for (int c = 0; c < 8; ++c) {
        float xv[4];
#pragma unroll
        for (int reg = 0; reg < 4; ++reg) {
          float x = acc[r][c][reg] + gr[r][reg] * wgr[c] + c0r[c];
          x = fmaxf(x, 0.f);
          if (e0 + reg >= NE) x = 0.f;
          xv[reg] = x;
          st_s[c] += x; st_q[c] += x * x;
        }
        unsigned b01 = packf16(xv[0], xv[1]);
        unsigned b23 = packf16(xv[2], xv[3]);
        unsigned q01 = (unsigned)__shfl_xor((int)b01, 1);
        unsigned q23 = (unsigned)__shfl_xor((int)b23, 1);
        const int ce = (c * 16 + m15) & ~1;
        if (!(m15 & 1)) {
          if (e0 < NE)     *(unsigned*)(x1 + (size_t)e0 * H1 + ce)       = (b01 & 0xffffu) | (q01 << 16);
          if (e0 + 1 < NE) *(unsigned*)(x1 + (size_t)(e0 + 1) * H1 + ce) = (b01 >> 16) | (q01 & 0xffff0000u);
        } else {
          if (e0 + 2 < NE) *(unsigned*)(x1 + (size_t)(e0 + 2) * H1 + ce) = (q23 & 0xffffu) | (b23 << 16);
          if (e0 + 3 < NE) *(unsigned*)(x1 + (size_t)(e0 + 3) * H1 + ce) = (q23 >> 16) | (b23 & 0xffff0000u);
        }
      }
    }
    // rotate next-tile state
    pu[0] = pun[0]; pu[1] = pun[1]; pv[0] = pvn[0]; pv[1] = pvn[1];
    gr[0] = grn[0]; gr[1] = grn[1];
    tile += GRID1;
  }

  __syncthreads();
#pragma unroll
  for (int c = 0; c < 8; ++c) {
    float a = st_s[c]; a += __shfl_xor(a, 16); a += __shfl_xor(a, 32);
    float b = st_q[c]; b += __shfl_xor(b, 16); b += __shfl_xor(b, 32);
    if (lane < 16) { atomicAdd(&s_sum[c * 16 + m15], a); atomicAdd(&s_sq[c * 16 + m15], b); }
  }
  __syncthreads();
  if (t < 128) {
    p1[t * GRID1 + bid] = s_sum[t];
    p1[128 * GRID1 + t * GRID1 + bid] = s_sq[t];
  }
}

// Finalize BN1 stats, fold into W2/b2 (fp32 row-major out)
__global__ void k_fin1(const float* __restrict__ p1, const float* __restrict__ g1,
                       const float* __restrict__ be1, const float* __restrict__ W2,
                       const float* __restrict__ b2, float* __restrict__ w2f,
                       float* __restrict__ b2f) {
  __shared__ float s1[128], t1[128];
  const int t = threadIdx.x;
  if (t < 128) {
    float s = 0.f, q = 0.f;
    const float4* rs = (const float4*)(p1 + t * GRID1);
    const float4* rq = (const float4*)(p1 + 128 * GRID1 + t * GRID1);
#pragma unroll 4
    for (int i = 0; i < GRID1 / 4; ++i) {
      float4 a = rs[i]; s += a.x + a.y + a.z + a.w;
      float4 b = rq[i]; q += b.x + b.y + b.z + b.w;
    }
    const float inv = 1.0f / (float)NE;
    float mean = s * inv;
    float var = q * inv - mean * mean;
    float sc = g1[t] * rsqrtf(var + EPSBN);
    s1[t] = sc; t1[t] = be1[t] - mean * sc;
  }
  __syncthreads();
  for (int i = t; i < H1 * H2; i += 256) w2f[i] = s1[i >> 6] * W2[i];
  if (t < 64) {
    float b = b2[t];
    for (int j = 0; j < 128; ++j) b += t1[j] * W2[j * 64 + t];
    b2f[t] = b;
  }
}

// Layer 2 via MFMA: x2 = relu(x1 @ W2F + b2F), B (16KB) in LDS.
// 256-edge jobs, wave owns 64 edges x 64 cols (acc[4][4]); one-job-ahead
// A prefetch via alternating register sets; packed dword stores.
__global__ __launch_bounds__(256, 2)
void k_layer2(const _Float16* __restrict__ x1, const float* __restrict__ w2f,
              const float* __restrict__ b2f, _Float16* __restrict__ x2,
              float* __restrict__ p2) {
  __shared__ __align__(16) _Float16 b_lds[8192];
  __shared__ float s_b[64], s_sum[64], s_sq[64];
  const int t = threadIdx.x, bid = blockIdx.x;
  const int w = t >> 6, lane = t & 63, quad = lane >> 4, m15 = lane & 15;

  for (int i = t; i < 8192; i += 256) {
    const int j = i & 7, li = (i >> 3) & 63, f = i >> 9;
    const int c = f & 3, kk = f >> 2;
    const int row = kk * 32 + (li >> 4) * 8 + j;
    const int col = c * 16 + (li & 15);
    b_lds[i] = (_Float16)w2f[row * H2 + col];
  }
  if (t < 64) { s_b[t] = b2f[t]; s_sum[t] = 0.f; s_sq[t] = 0.f; }
  __syncthreads();

  float bvr[4];
#pragma unroll
  for (int c = 0; c < 4; ++c) bvr[c] = s_b[c * 16 + m15];

  float st_s[4] = {0, 0, 0, 0}, st_q[4] = {0, 0, 0, 0};
  const half8* bp = (const half8*)b_lds;

  half8 a0[4][4], a1[4][4];   // [kk][r]

#define L2LOAD(A, bb) do {                                                    \
    _Pragma("unroll")                                                         \
    for (int r = 0; r < 4; ++r) {                                             \
      int e_ = (bb) + w * 64 + r * 16 + m15; if (e_ >= NE) e_ = NE - 1;       \
      const _Float16* p_ = x1 + (size_t)e_ * H1 + quad * 8;                   \
      _Pragma("unroll")                                                       \
      for (int kk = 0; kk < 4; ++kk) (A)[kk][r] = *(const half8*)(p_ + kk * 32); \
    } } while (0)

#define L2COMP(A, bb) do {                                                    \
    f32x4 acc[4][4];                                                          \
    _Pragma("unroll")                                                         \
    for (int r = 0; r < 4; ++r)                                               \
      _Pragma("unroll")                                                       \
      for (int c = 0; c < 4; ++c) acc[r][c] = (f32x4)0.f;                     \
    _Pragma("unroll")                                                         \
    for (int kk = 0; kk < 4; ++kk)                                            \
      _Pragma("unroll")                                                       \
      for (int c = 0; c < 4; ++c) {                                           \
        half8 bf = bp[(kk * 4 + c) * 64 + lane];                              \
        _Pragma("unroll")                                                     \
        for (int r = 0; r < 4; ++r)                                           \
          acc[r][c] = __builtin_amdgcn_mfma_f32_16x16x32_f16((A)[kk][r], bf, acc[r][c], 0, 0, 0); \
      }                                                                       \
    _Pragma("unroll")                                                         \
    for (int r = 0; r < 4; ++r) {                                             \
      const int e0 = (bb) + w * 64 + r * 16 + quad * 4;                       \
      _Pragma("unroll")                                                       \
      for (int c = 0; c < 4; ++c) {                                           \
        float xv[4];                                                          \
        _Pragma("unroll")                                                     \
        for (int reg = 0; reg < 4; ++reg) {                                   \
          float x = acc[r][c][reg] + bvr[c];                                  \
          x = fmaxf(x, 0.f);                                                  \
          if (e0 + reg >= NE) x = 0.f;                                        \
          xv[reg] = x; st_s[c] += x; st_q[c] += x * x;                        \
        }                                                                     \
        unsigned b01 = packf16(xv[0], xv[1]);                                 \
        unsigned b23 = packf16(xv[2], xv[3]);                                 \
        unsigned q01 = (unsigned)__shfl_xor((int)b01, 1);                     \
        unsigned q23 = (unsigned)__shfl_xor((int)b23, 1);                     \
        const int ce = (c * 16 + m15) & ~1;                                   \
        if (!(m15 & 1)) {                                                     \
          if (e0 < NE)     *(unsigned*)(x2 + (size_t)e0 * H2 + ce)       = (b01 & 0xffffu) | (q01 << 16); \
          if (e0 + 1 < NE) *(unsigned*)(x2 + (size_t)(e0 + 1) * H2 + ce) = (b01 >> 16) | (q01 & 0xffff0000u); \
        } else {                                                              \
          if (e0 + 2 < NE) *(unsigned*)(x2 + (size_t)(e0 + 2) * H2 + ce) = (q23 & 0xffffu) | (b23 << 16); \
          if (e0 + 3 < NE) *(unsigned*)(x2 + (size_t)(e0 + 3) * H2 + ce) = (q23 >> 16) | (b23 & 0xffff0000u); \
        }                                                                     \
      }                                                                       \
    } } while (0)

  int j = bid;
  if (j < NJ2) {
    L2LOAD(a0, j * 256);
    while (j < NJ2) {
      const int j1 = j + GRID2;
      L2LOAD(a1, (j1 < NJ2 ? j1 : j) * 256);
      L2COMP(a0, j * 256);
      if (j1 >= NJ2) break;
      const int j2 = j1 + GRID2;
      L2LOAD(a0, (j2 < NJ2 ? j2 : j1) * 256);
      L2COMP(a1, j1 * 256);
      j = j2;
    }
  }
#undef L2LOAD
#undef L2COMP

  __syncthreads();
#pragma unroll
  for (int c = 0; c < 4; ++c) {
    float a = st_s[c]; a += __shfl_xor(a, 16); a += __shfl_xor(a, 32);
    float b = st_q[c]; b += __shfl_xor(b, 16); b += __shfl_xor(b, 32);
    if (lane < 16) { atomicAdd(&s_sum[c * 16 + m15], a); atomicAdd(&s_sq[c * 16 + m15], b); }
  }
  __syncthreads();
  if (t < 64) {
    p2[t * GRID2 + bid] = s_sum[t];
    p2[64 * GRID2 + t * GRID2 + bid] = s_sq[t];
  }
}

// Finalize BN2, fold into W3/b3
__global__ void k_fin2(const float* __restrict__ p2, const float* __restrict__ g2,
                       const float* __restrict__ be2, const float* __restrict__ W3,
                       const float* __restrict__ b3, float* __restrict__ w3f,
                       float* __restrict__ b3f) {
  __shared__ float tp[64];
  const int t = threadIdx.x;
  if (t < 64) {
    float s = 0.f, q = 0.f;
    const float4* rs = (const float4*)(p2 + t * GRID2);
    const float4* rq = (const float4*)(p2 + 64 * GRID2 + t * GRID2);
#pragma unroll 4
    for (int i = 0; i < GRID2 / 4; ++i) {
      float4 a = rs[i]; s += a.x + a.y + a.z + a.w;
      float4 b = rq[i]; q += b.x + b.y + b.z + b.w;
    }
    const float inv = 1.0f / (float)NE;
    float mean = s * inv;
    float var = q * inv - mean * mean;
    float sc = g2[t] * rsqrtf(var + EPSBN);
    float tt = be2[t] - mean * sc;
    w3f[t] = sc * W3[t];
    tp[t] = tt * W3[t];
  }
  __syncthreads();
  if (t == 0) {
    float b = b3[0];
    for (int j = 0; j < 64; ++j) b += tp[j];
    b3f[0] = b;
  }
}

// out = tanh(x2 @ w3f + b3f); 4 lanes per edge
__global__ __launch_bounds__(256)
void k_out(const unsigned short* __restrict__ x2, const float* __restrict__ w3f,
           const float* __restrict__ b3f, float* __restrict__ out) {
  __shared__ float s_w[64];
  __shared__ float s_b;
  const int t = threadIdx.x;
  if (t < 64) s_w[t] = w3f[t];
  if (t == 0) s_b = b3f[0];
  __syncthreads();
  const int gid = blockIdx.x * 256 + t;
  const int e = gid >> 2, p = gid & 3;
  if (e < NE) {
    const uint4* r = (const uint4*)(x2 + (size_t)e * H2 + p * 16);
    float s = 0.f;
#pragma unroll
    for (int i = 0; i < 2; ++i) {
      const uint4 u = r[i];
      const int jb = p * 16 + i * 8;
      s += h2f(u.x) * s_w[jb + 0] + h2f(u.x >> 16) * s_w[jb + 1];
      s += h2f(u.y) * s_w[jb + 2] + h2f(u.y >> 16) * s_w[jb + 3];
      s += h2f(u.z) * s_w[jb + 4] + h2f(u.z >> 16) * s_w[jb + 5];
      s += h2f(u.w) * s_w[jb + 6] + h2f(u.w >> 16) * s_w[jb + 7];
    }
    s += __shfl_xor(s, 1);
    s += __shfl_xor(s, 2);
    if (p == 0) out[e] = tanhf(s + s_b);
  }
}

extern "C" void kernel_launch(void* const* d_in, const int* in_sizes, int n_in,
                              void* d_out, int out_size, void* d_ws, size_t ws_size,
                              hipStream_t stream) {
  const float* emb  = (const float*)d_in[0];
  const float* grad = (const float*)d_in[1];
  const float* step = (const float*)d_in[2];
  const float* W1   = (const float*)d_in[3];
  const float* b1   = (const float*)d_in[4];
  const float* g1   = (const float*)d_in[5];
  const float* be1  = (const float*)d_in[6];
  const float* W2   = (const float*)d_in[7];
  const float* b2   = (const float*)d_in[8];
  const float* g2   = (const float*)d_in[9];
  const float* be2  = (const float*)d_in[10];
  const float* W3   = (const float*)d_in[11];
  const float* b3   = (const float*)d_in[12];
  const void*  eidx = (const void*)d_in[13];
  float* out = (float*)d_out;

  char* ws = (char*)d_ws;
  // region A (64MB): embh (25.6MB) + bfrag + c0 + p1 during layer1/fin1;
  // x2 overwrites the whole region in layer2.
  _Float16* embh  = (_Float16*)(ws + 0);
  _Float16* x2    = (_Float16*)(ws + 0);
  _Float16* bfrag = (_Float16*)(ws + 25600000LL);  // 196,608 B
  float*    c0    = (float*)(ws + 25796608LL);     // 512 B
  float*    p1    = (float*)(ws + 26000000LL);     // 524,288 B (dead before layer2)
  _Float16* x1    = (_Float16*)(ws + 64000000LL);  // 128,000,000 B
  float* p2  = (float*)(ws + 192000000LL);         // 262,144 B
  float* w2f = (float*)(ws + 192524288LL);         // 32,768 B
  float* b2f = (float*)(ws + 192557056LL);         // 256 B
  float* w3f = (float*)(ws + 192557312LL);         // 256 B
  float* b3f = (float*)(ws + 192557568LL);         // 16 B

  k_prep  <<<1,    256, 0, stream>>>(W1, b1, step, c0);
  k_prep16<<<6250, 256, 0, stream>>>(emb, embh);
  k_prepB <<<48,   256, 0, stream>>>(W1, bfrag);
  k_layer1<<<GRID1,256, 0, stream>>>(embh, eidx, grad, W1, c0, bfrag, x1, p1);
  k_fin1  <<<1,    256, 0, stream>>>(p1, g1, be1, W2, b2, w2f, b2f);
  k_layer2<<<GRID2,256, 0, stream>>>(x1, w2f, b2f, x2, p2);
  k_fin2  <<<1,    128, 0, stream>>>(p2, g2, be2, W3, b3, w3f, b3f);
  k_out   <<<7813, 256, 0, stream>>>((const unsigned short*)x2, w3f, b3f, out);
}